// Round 7
// baseline (3041.429 us; speedup 1.0000x reference)
//
#include <hip/hip_runtime.h>

typedef unsigned int  u32;
typedef unsigned short u16;
typedef unsigned long long u64;
typedef _Float16 half8 __attribute__((ext_vector_type(8)));
typedef short   short8 __attribute__((ext_vector_type(8)));
typedef float   f32x4  __attribute__((ext_vector_type(4)));

#define T_LEN 512
#define BATCH 64
#define EDIM  256
#define HDIM  256
#define G4    1024   // 4*H gate rows

// ---------- numeric helpers ----------
static __device__ __forceinline__ u16 f2bf(float f) {
  u32 u = __builtin_bit_cast(u32, f);
  u = (u + 0x7fffu + ((u >> 16) & 1u)) >> 16;   // RTNE
  return (u16)u;
}
static __device__ __forceinline__ u16 f2h(float a) {
  _Float16 ha = (_Float16)a;
  return __builtin_bit_cast(u16, ha);
}
static __device__ __forceinline__ float h2f(u16 a) {
  return (float)__builtin_bit_cast(_Float16, a);
}
static __device__ __forceinline__ float sigf(float x) {
  return 1.0f / (1.0f + __expf(-x));
}
static __device__ __forceinline__ float tanhfast(float x) {
  return 2.0f / (1.0f + __expf(-2.0f * x)) - 1.0f;
}

// ---------- kernel 1: pack W_hh_f into f16 MFMA A-frag order -----------------
// Wf[mt][kt][lane][j]: flat ((mt*8+kt)*64+lane)*8+j; value =
// W[mt*16+(lane&15)][kt*32+(lane>>4)*8+j].  kt==7 frags also packed
// contiguously: Wst[(j16*4+q)][lane][j], mt = q*16 + j16 (1 KB stride).
__global__ __launch_bounds__(256) void k_prep(const float* __restrict__ whh,
                                              u16* __restrict__ Wf,
                                              u16* __restrict__ Wst) {
  int cell = blockIdx.x * 256 + threadIdx.x;  // 32768 cells, 8 f16 each
  int mt = cell >> 9, kt = (cell >> 6) & 7, l = cell & 63;
  int gr = mt * 16 + (l & 15);
  int c0 = kt * 32 + (l >> 4) * 8;
  const float4* src = (const float4*)(whh + (size_t)gr * 256 + c0);
  float4 a = src[0], b = src[1];
  u16 o[8] = { f2h(a.x), f2h(a.y), f2h(a.z), f2h(a.w),
               f2h(b.x), f2h(b.y), f2h(b.z), f2h(b.w) };
  *(uint4*)(Wf + (size_t)cell * 8) = *(uint4*)o;
  if (kt == 7) {
    int q = mt >> 4, j16 = mt & 15;
    *(uint4*)(Wst + ((size_t)(j16 * 4 + q) * 64 + l) * 8) = *(uint4*)o;
  }
}

// ---------- kernel 2: xproj via bf16 MFMA, f16 out in k_rnn D-frag order -----
// xp2[t][bg][mt'][lane][r] with mt' = j16*4 + q  (q=gate, j16=row-block).
#define LDSPITCH 264
__global__ __launch_bounds__(256) void k_xproj(const int* __restrict__ x,
                                               const float* __restrict__ emb,
                                               const float* __restrict__ wih,
                                               const float* __restrict__ bih,
                                               const float* __restrict__ bhh,
                                               u16* __restrict__ xp2) {
  __shared__ u16 smA[64 * LDSPITCH];
  __shared__ u16 smB[64 * LDSPITCH];
  const int tn = blockIdx.x, t = blockIdx.y;
  const int tid = threadIdx.x;
  const int r = tid >> 2, q4 = tid & 3;

  { // stage A: emb rows (batch r, timestep t), fp32 -> bf16
    int eidx = x[r * T_LEN + t];
    const float4* src = (const float4*)(emb + (size_t)eidx * EDIM + q4 * 64);
    u16* dst = smA + r * LDSPITCH + q4 * 64;
    #pragma unroll
    for (int i = 0; i < 16; ++i) {
      float4 v = src[i];
      uint2 p;
      p.x = (u32)f2bf(v.x) | ((u32)f2bf(v.y) << 16);
      p.y = (u32)f2bf(v.z) | ((u32)f2bf(v.w) << 16);
      *(uint2*)&dst[i * 4] = p;
    }
  }
  { // stage B: w_ih rows g = tn*64 + r
    const float4* src = (const float4*)(wih + (size_t)(tn * 64 + r) * EDIM + q4 * 64);
    u16* dst = smB + r * LDSPITCH + q4 * 64;
    #pragma unroll
    for (int i = 0; i < 16; ++i) {
      float4 v = src[i];
      uint2 p;
      p.x = (u32)f2bf(v.x) | ((u32)f2bf(v.y) << 16);
      p.y = (u32)f2bf(v.z) | ((u32)f2bf(v.w) << 16);
      *(uint2*)&dst[i * 4] = p;
    }
  }
  __syncthreads();

  const int wv = tid >> 6, lane = tid & 63;
  const int lm = lane & 15, q = lane >> 4;
  f32x4 acc[4];
  #pragma unroll
  for (int nt = 0; nt < 4; ++nt) acc[nt] = (f32x4){0.f, 0.f, 0.f, 0.f};

  const u16* pa = smA + (wv * 16 + lm) * LDSPITCH + q * 8;
  const u16* pb = smB + lm * LDSPITCH + q * 8;
  #pragma unroll
  for (int ks = 0; ks < 8; ++ks) {
    short8 av = *(const short8*)(pa + ks * 32);
    #pragma unroll
    for (int nt = 0; nt < 4; ++nt) {
      short8 bv = *(const short8*)(pb + nt * 16 * LDSPITCH + ks * 32);
      acc[nt] = __builtin_amdgcn_mfma_f32_16x16x32_bf16(av, bv, acc[nt], 0, 0, 0);
    }
  }
  // D: row = batch = wv*16+q*4+rr, col = gate row g = tn*64+nt*16+lm.
  #pragma unroll
  for (int nt = 0; nt < 4; ++nt) {
    int g = tn * 64 + nt * 16 + lm;
    float bias = bih[g] + bhh[g];
    int gq = g >> 8, j16 = (g >> 4) & 15, qd = (g & 15) >> 2, rb = g & 3;
    int mtp = j16 * 4 + gq;
    #pragma unroll
    for (int rr = 0; rr < 4; ++rr) {
      int bl = q * 4 + rr;   // batch-in-group; bg = wv
      size_t idx = ((((size_t)t * 4 + wv) * 64 + mtp) * 64 + (qd * 16 + bl)) * 4 + rb;
      xp2[idx] = f2h(acc[nt][rr] + bias);
    }
  }
}

// ---------- kernel 3: recurrence, 4 WGs x 512 thr, no cross-WG sync ----------
// WG bg owns batches [bg*16,+16). Wave v owns row-blocks j = 2v,2v+1
// (m-tiles mt = q*16 + j), two passes p. Weights: kt0-4 RF (40 frags pinned),
// kt5-6 LDS (frag-contiguous), kt7 streamed from Wst (imm offsets).
// h kept in LDS in MFMA-B-FRAG ORDER [kt][lane][8] -> conflict-free b128 reads
// at base + kt*1KB (imm), conflict-free b64 writes. 2 barriers/step.
__global__ __launch_bounds__(512, 2) void k_rnn(const u16* __restrict__ Wf,
                                                const u16* __restrict__ Wst,
                                                const u16* __restrict__ xp2,
                                                float* __restrict__ hf) {
  extern __shared__ u16 sm[];
  u16* smW = sm;               // 65536 u16 = 128 KB: fid = v*16+(p*4+q)*2+(kt-5)
  u16* smH = sm + 65536;       // 8192 u16 = 16 KB: h in B-frag order [kt][lane][8]
  const int bg = blockIdx.x;
  const int tid = threadIdx.x;
  const int v = tid >> 6, l = tid & 63;
  const int bl = l & 15, qd = l >> 4;

  // ---- stage resident (kt0-4) and LDS (kt5-6) weight frags ----
  half8 Wr[2][4][5];
  #pragma unroll
  for (int p = 0; p < 2; ++p) {
    int j = 2 * v + p;
    #pragma unroll
    for (int q = 0; q < 4; ++q) {
      #pragma unroll
      for (int kt = 0; kt < 5; ++kt)
        Wr[p][q][kt] = *(const half8*)(Wf + ((size_t)((q * 16 + j) * 8 + kt) * 64 + l) * 8);
      #pragma unroll
      for (int kt = 5; kt < 7; ++kt) {
        uint4 tv = *(const uint4*)(Wf + ((size_t)((q * 16 + j) * 8 + kt) * 64 + l) * 8);
        *(uint4*)(smW + ((size_t)(v * 16 + (p * 4 + q) * 2 + (kt - 5)) * 64 + l) * 8) = tv;
      }
    }
  }
  // opacity pin: values unknown -> rematerialization from Wf illegal
  #pragma unroll
  for (int p = 0; p < 2; ++p)
    #pragma unroll
    for (int q = 0; q < 4; ++q)
      asm volatile("" : "+v"(Wr[p][q][0]), "+v"(Wr[p][q][1]), "+v"(Wr[p][q][2]),
                        "+v"(Wr[p][q][3]), "+v"(Wr[p][q][4]));

  { // zero h buffer (8192 u16 = 4096 u32)
    u32* hz = (u32*)smH;
    #pragma unroll
    for (int k = 0; k < 8; ++k) { int i = tid + k * 512; if (i < 4096) hz[i] = 0; }
  }
  __syncthreads();

  float c[2][4];
  #pragma unroll
  for (int p = 0; p < 2; ++p)
    #pragma unroll
    for (int r = 0; r < 4; ++r) c[p][r] = 0.f;

  // bases (all hot-loop accesses are base + immediate offset)
  const u16* xb   = xp2 + (size_t)bg * 16384 + v * 2048 + (size_t)l * 4; // +(4p+q)*256
  const u16* wp0  = Wst + (size_t)v * 4096 + (size_t)l * 8;              // +q*512
  const u16* wp1  = wp0 + 2048;
  const u16* hb   = smH + (size_t)l * 8;                                 // +kt*512
  const u16* smwb = smW + (size_t)v * 8192 + (size_t)l * 8;              // +fid*512
  // h write: frag kt = v, lane_t = (p*2+(qd>>1))*16+bl, j_t = (qd&1)*4
  u16* hw = smH + (size_t)v * 512 + ((size_t)((qd >> 1) * 16 + bl)) * 8 + (qd & 1) * 4;

  for (int t = 0; t < T_LEN; ++t) {
    uint2 hpk[2];
    #pragma unroll
    for (int p = 0; p < 2; ++p) {
      const u16* wpp = p ? wp1 : wp0;
      // stream kt7 A-frags now; consumed 7 kts later (L2 latency hidden)
      uint4 As0 = *(const uint4*)(wpp);
      uint4 As1 = *(const uint4*)(wpp + 512);
      uint4 As2 = *(const uint4*)(wpp + 1024);
      uint4 As3 = *(const uint4*)(wpp + 1536);

      f32x4 a0 = (f32x4){0.f,0.f,0.f,0.f}, a1 = a0, a2 = a0, a3 = a0;
      #pragma unroll
      for (int kt = 0; kt < 5; ++kt) {
        half8 Bf = *(const half8*)(hb + kt * 512);
        a0 = __builtin_amdgcn_mfma_f32_16x16x32_f16(Wr[p][0][kt], Bf, a0, 0, 0, 0);
        a1 = __builtin_amdgcn_mfma_f32_16x16x32_f16(Wr[p][1][kt], Bf, a1, 0, 0, 0);
        a2 = __builtin_amdgcn_mfma_f32_16x16x32_f16(Wr[p][2][kt], Bf, a2, 0, 0, 0);
        a3 = __builtin_amdgcn_mfma_f32_16x16x32_f16(Wr[p][3][kt], Bf, a3, 0, 0, 0);
      }
      #pragma unroll
      for (int kt = 5; kt < 7; ++kt) {
        half8 Bf = *(const half8*)(hb + kt * 512);
        half8 w0 = *(const half8*)(smwb + ((p * 4 + 0) * 2 + (kt - 5)) * 512);
        half8 w1 = *(const half8*)(smwb + ((p * 4 + 1) * 2 + (kt - 5)) * 512);
        half8 w2 = *(const half8*)(smwb + ((p * 4 + 2) * 2 + (kt - 5)) * 512);
        half8 w3 = *(const half8*)(smwb + ((p * 4 + 3) * 2 + (kt - 5)) * 512);
        a0 = __builtin_amdgcn_mfma_f32_16x16x32_f16(w0, Bf, a0, 0, 0, 0);
        a1 = __builtin_amdgcn_mfma_f32_16x16x32_f16(w1, Bf, a1, 0, 0, 0);
        a2 = __builtin_amdgcn_mfma_f32_16x16x32_f16(w2, Bf, a2, 0, 0, 0);
        a3 = __builtin_amdgcn_mfma_f32_16x16x32_f16(w3, Bf, a3, 0, 0, 0);
      }
      // xv loads (consumed after kt7)
      uint2 xv0 = *(const uint2*)(xb + (4 * p + 0) * 256);
      uint2 xv1 = *(const uint2*)(xb + (4 * p + 1) * 256);
      uint2 xv2 = *(const uint2*)(xb + (4 * p + 2) * 256);
      uint2 xv3 = *(const uint2*)(xb + (4 * p + 3) * 256);
      { // kt7 from streamed regs
        half8 Bf = *(const half8*)(hb + 7 * 512);
        a0 = __builtin_amdgcn_mfma_f32_16x16x32_f16(__builtin_bit_cast(half8, As0), Bf, a0, 0, 0, 0);
        a1 = __builtin_amdgcn_mfma_f32_16x16x32_f16(__builtin_bit_cast(half8, As1), Bf, a1, 0, 0, 0);
        a2 = __builtin_amdgcn_mfma_f32_16x16x32_f16(__builtin_bit_cast(half8, As2), Bf, a2, 0, 0, 0);
        a3 = __builtin_amdgcn_mfma_f32_16x16x32_f16(__builtin_bit_cast(half8, As3), Bf, a3, 0, 0, 0);
      }
      // gates; rows (2v+p)*16 + qd*4 + r, batch bg*16 + bl
      u16 hh[4];
      #pragma unroll
      for (int r = 0; r < 4; ++r) {
        u32 x0 = (r < 2) ? xv0.x : xv0.y;
        u32 x1 = (r < 2) ? xv1.x : xv1.y;
        u32 x2 = (r < 2) ? xv2.x : xv2.y;
        u32 x3 = (r < 2) ? xv3.x : xv3.y;
        const int sh = 16 * (r & 1);
        float zi = a0[r] + h2f((u16)(x0 >> sh));
        float zf = a1[r] + h2f((u16)(x1 >> sh));
        float zg = a2[r] + h2f((u16)(x2 >> sh));
        float zo = a3[r] + h2f((u16)(x3 >> sh));
        c[p][r] = sigf(zf) * c[p][r] + sigf(zi) * tanhfast(zg);
        float hn = sigf(zo) * tanhfast(c[p][r]);
        hh[r] = f2h(hn);
        if (t == T_LEN - 1)
          hf[(size_t)(bg * 16 + bl) * 256 + (2 * v + p) * 16 + qd * 4 + r] = hn;
      }
      hpk[p] = make_uint2((u32)hh[0] | ((u32)hh[1] << 16),
                          (u32)hh[2] | ((u32)hh[3] << 16));
    }
    __syncthreads();                 // all reads of h(t) complete
    *(uint2*)(hw)       = hpk[0];    // p=0 -> lane_t group 0/1
    *(uint2*)(hw + 256) = hpk[1];    // p=1 -> +2*16*8 u16
    __syncthreads();                 // h(t+1) visible
    xb += 65536;
  }
}

// ---------- kernel 4: backward single step + fc1 + fc2 ----------
__global__ __launch_bounds__(256) void k_tail(const int* __restrict__ x,
                                              const float* __restrict__ emb,
                                              const float* __restrict__ wihb,
                                              const float* __restrict__ bihb,
                                              const float* __restrict__ bhhb,
                                              const float* __restrict__ fc1w,
                                              const float* __restrict__ fc1b,
                                              const float* __restrict__ fc2w,
                                              const float* __restrict__ fc2b,
                                              const float* __restrict__ hf,
                                              float* __restrict__ out) {
  const int b = blockIdx.x, tid = threadIdx.x;
  __shared__ float e[EDIM], hb[HDIM], hfl[HDIM], f1[24];
  e[tid]   = emb[(size_t)x[b * T_LEN + (T_LEN - 1)] * EDIM + tid];
  hfl[tid] = hf[b * HDIM + tid];
  __syncthreads();

  float z[4];
  #pragma unroll
  for (int gq = 0; gq < 4; ++gq) {
    int g = gq * HDIM + tid;
    float s = bihb[g] + bhhb[g];
    const float4* wr = (const float4*)(wihb + (size_t)g * EDIM);
    #pragma unroll 8
    for (int k = 0; k < 64; ++k) {
      float4 w = wr[k];
      s += w.x * e[4 * k] + w.y * e[4 * k + 1] + w.z * e[4 * k + 2] + w.w * e[4 * k + 3];
    }
    z[gq] = s;
  }
  float cb = sigf(z[0]) * tanhfast(z[2]);   // c0 = 0
  hb[tid] = sigf(z[3]) * tanhfast(cb);
  __syncthreads();

  if (tid < 24) {
    float s = fc1b[tid];
    const float* w = fc1w + tid * 512;
    #pragma unroll 8
    for (int k = 0; k < HDIM; ++k) s += w[k] * hfl[k] + w[HDIM + k] * hb[k];
    f1[tid] = fmaxf(s, 0.f);
  }
  __syncthreads();
  if (tid < 2) {
    float s = fc2b[tid];
    #pragma unroll
    for (int k = 0; k < 24; ++k) s += fc2w[tid * 24 + k] * f1[k];
    out[b * 2 + tid] = s;
  }
}

// ---------- launch ----------
extern "C" void kernel_launch(void* const* d_in, const int* in_sizes, int n_in,
                              void* d_out, int out_size, void* d_ws, size_t ws_size,
                              hipStream_t stream) {
  const int*   x     = (const int*)  d_in[0];
  const float* emb   = (const float*)d_in[1];
  const float* wih_f = (const float*)d_in[2];
  const float* whh_f = (const float*)d_in[3];
  const float* bih_f = (const float*)d_in[4];
  const float* bhh_f = (const float*)d_in[5];
  const float* wih_b = (const float*)d_in[6];
  // d_in[7] = w_hh_b: unused (backward runs exactly one step from zero state)
  const float* bih_b = (const float*)d_in[8];
  const float* bhh_b = (const float*)d_in[9];
  const float* fc1w  = (const float*)d_in[10];
  const float* fc1b  = (const float*)d_in[11];
  const float* fc2w  = (const float*)d_in[12];
  const float* fc2b  = (const float*)d_in[13];
  float* out = (float*)d_out;

  // workspace: xp2 64 MiB | Wf 512 KiB | Wst 64 KiB | hf 64 KiB
  char* ws = (char*)d_ws;
  u16*   xp2 = (u16*)ws;
  u16*   Wf  = (u16*)(ws + 67108864);
  u16*   Wst = (u16*)(ws + 67108864 + 524288);
  float* hf  = (float*)(ws + 67108864 + 524288 + 65536);

  k_prep <<<128, 256, 0, stream>>>(whh_f, Wf, Wst);
  k_xproj<<<dim3(16, 512), 256, 0, stream>>>(x, emb, wih_f, bih_f, bhh_f, xp2);
  k_rnn  <<<4, 512, 147456, stream>>>(Wf, Wst, xp2, hf);
  k_tail <<<BATCH, 256, 0, stream>>>(x, emb, wih_b, bih_b, bhh_b,
                                     fc1w, fc1b, fc2w, fc2b, hf, out);
}